// Round 11
// baseline (289.471 us; speedup 1.0000x reference)
//
#include <hip/hip_runtime.h>
#include <math.h>

#define N_PIX 2304
#define CCH   256
#define BHN   16     // B * NHEAD
#define KTOP  576
#define NROWS 4608   // B * N_PIX

typedef unsigned short u16;
typedef __attribute__((ext_vector_type(8))) short short8v;   // 8 bf16
typedef __attribute__((ext_vector_type(4))) float floatx4;

__device__ __forceinline__ u16 f2b(float f) {
  unsigned int u = __float_as_uint(f);
  return (u16)((u + 0x7fffu + ((u >> 16) & 1u)) >> 16);      // RNE
}
__device__ __forceinline__ float b2f(u16 v) {
  return __uint_as_float(((unsigned int)v) << 16);
}

// float-only erf (A&S 7.1.26, |err|<=1.5e-7)
__device__ __forceinline__ float erf_apx(float x) {
  float ax = fabsf(x);
  float u = 1.f / (1.f + 0.3275911f * ax);
  float y = u * (0.254829592f + u * (-0.284496736f + u * (1.421413741f +
            u * (-1.453152027f + u * 1.061405429f))));
  float r = 1.f - y * expf(-ax * ax);
  return (x < 0.f) ? -r : r;
}

// ============ fused: ln1 (blocks 0..143) + weight casts (144..3535) + zero (3536)
// B2 combo: B2[n][k<256] = out_w[k][n] ; B2[n][256+i] = pw_w[n][i]
__global__ __launch_bounds__(256) void lncast_kernel(
    const float* __restrict__ x, u16* __restrict__ xa_bf, float* __restrict__ xnhwc,
    const float* __restrict__ g, const float* __restrict__ beta,
    const float* __restrict__ qkv_w, const float* __restrict__ out_w,
    const float* __restrict__ pw_w, const float* __restrict__ ff_w1,
    const float* __restrict__ ff_w2, const float* __restrict__ sg1_w,
    u16* __restrict__ qkvBT, u16* __restrict__ B2,
    u16* __restrict__ ff1BT, u16* __restrict__ ff2BT, u16* __restrict__ sg1BT,
    float* __restrict__ zbuf)
{
  __shared__ float tile[32 * 257];
  __shared__ float redS[8 * 32], redQ[8 * 32];
  __shared__ float mu_s[32], rs_s[32];
  int tid = threadIdx.x;
  if (blockIdx.x == 3536) {     // ---- zero csum/vneg/cgm (consumed next launch+)
#pragma unroll
    for (int j = 0; j < 10; ++j) zbuf[tid + j * 256] = 0.f;
    return;
  }
  if (blockIdx.x >= 144) {      // ---- weight-cast part ----
    int i = (blockIdx.x - 144) * 256 + tid;
    if (i < 196608) { int k = i / 768, n = i - k * 768; qkvBT[n * 256 + k] = f2b(qkv_w[i]); return; }
    i -= 196608;
    if (i < 65536) { int k = i >> 8, n = i & 255; B2[n * 512 + k] = f2b(out_w[i]); return; }
    i -= 65536;
    if (i < 65536) { int n = i >> 8, ic = i & 255; B2[n * 512 + 256 + ic] = f2b(pw_w[i]); return; }
    i -= 65536;
    if (i < 262144) { int k = i >> 10, n = i & 1023; ff1BT[n * 256 + k] = f2b(ff_w1[i]); return; }
    i -= 262144;
    if (i < 262144) { int k = i & 1023, n = i >> 10; ff2BT[i] = f2b(ff_w2[k * 256 + n]); return; }
    i -= 262144;
    if (i < 16384) sg1BT[i] = (i < 8192) ? f2b(sg1_w[i]) : (u16)0;
    return;
  }
  // ---- ln1 part ----
  int p0g = blockIdx.x * 32;
  int bb = p0g / N_PIX; int p0 = p0g - bb * N_PIX;
  int px = tid & 31, csub = tid >> 5;
  float sacc = 0.f, qacc = 0.f;
#pragma unroll 4
  for (int it = 0; it < 32; ++it) {
    int c = it * 8 + csub;
    float v = x[((long)bb * 256 + c) * N_PIX + p0 + px];
    tile[px * 257 + c] = v;
    sacc += v; qacc += v * v;
  }
  redS[csub * 32 + px] = sacc; redQ[csub * 32 + px] = qacc;
  __syncthreads();
  if (tid < 32) {
    float s = 0.f, qq = 0.f;
#pragma unroll
    for (int j = 0; j < 8; ++j) { s += redS[j * 32 + tid]; qq += redQ[j * 32 + tid]; }
    float mu = s * (1.f / 256.f);
    float var = qq * (1.f / 256.f) - mu * mu;
    mu_s[tid] = mu; rs_s[tid] = rsqrtf(var + 1e-6f);
  }
  __syncthreads();
  float gv = g[tid], bv = beta[tid];
#pragma unroll 4
  for (int it = 0; it < 32; ++it) {
    float v = tile[it * 257 + tid];
    long orow = (long)(p0g + it) * 256 + tid;
    xnhwc[orow] = v;
    xa_bf[orow] = f2b((v - mu_s[it]) * rs_s[it] * gv + bv);
  }
}

// ============ DIRECT bf16 MFMA GEMM — no LDS, no barriers =============
// C[M,N] = A[M,K] @ BT[N,K]^T. Block: (MT*64) rows x 64 cols, 4 waves.
// Wave w owns rows row0 + w*(16*MT) .. +16*MT. Fragments loaded straight
// from global (16B/lane, pipelined by compiler vmcnt — no barrier drain).
// EPI 0: C fp32 = acc                      (CS: col-sums -> cs_out)
// EPI 3: silu(acc+bias) -> C fp32, cols < nvalid
// EPI 4: gelu(acc+bias) -> C2 bf16
// EPI 5: out NCHW = [xnhwc + g1*xs*sg*cg] + gamma*(acc+bias)
// EPI 7: acc+bias -> C2 bf16               (CS: col-sums)
template<int MT, int EPI, int CS>
__global__ __launch_bounds__(256) void dgemm(
    const u16* __restrict__ A, const u16* __restrict__ BT,
    float* __restrict__ C, u16* __restrict__ C2,
    int K, int ldc, int nvalid,
    const float* __restrict__ bias, const float* __restrict__ add,
    const float* __restrict__ gamma,
    float* __restrict__ cs_out, int cs_ld,
    const u16* __restrict__ xs2, const float* __restrict__ sgv,
    const float* __restrict__ cgv, const float* __restrict__ g1p)
{
  int tid = threadIdx.x;
  int w = tid >> 6, lane = tid & 63;
  int q = lane >> 4, l15 = lane & 15;
  int row0 = blockIdx.y * (MT * 64), col0 = blockIdx.x * 64;

  floatx4 acc[MT][4];
#pragma unroll
  for (int mi = 0; mi < MT; ++mi)
#pragma unroll
    for (int ni = 0; ni < 4; ++ni) acc[mi][ni] = (floatx4)0.f;

  const u16* Ap = A + (long)(row0 + w * (16 * MT) + l15) * K + q * 8;
  const u16* Bp = BT + (long)(col0 + l15) * K + q * 8;

#pragma unroll 2
  for (int k0 = 0; k0 < K; k0 += 32) {
    short8v a[MT], b[4];
#pragma unroll
    for (int mi = 0; mi < MT; ++mi)
      a[mi] = *(const short8v*)(Ap + (long)mi * 16 * K + k0);
#pragma unroll
    for (int ni = 0; ni < 4; ++ni)
      b[ni] = *(const short8v*)(Bp + (long)ni * 16 * K + k0);
#pragma unroll
    for (int ni = 0; ni < 4; ++ni)
#pragma unroll
      for (int mi = 0; mi < MT; ++mi)
        acc[mi][ni] = __builtin_amdgcn_mfma_f32_16x16x32_bf16(a[mi], b[ni], acc[mi][ni], 0, 0, 0);
  }

  float g2 = (EPI == 5) ? gamma[0] : 0.f;
  float g1v = (EPI == 5) ? g1p[0] : 0.f;
  float cp[4] = {0.f, 0.f, 0.f, 0.f};
#pragma unroll
  for (int mi = 0; mi < MT; ++mi) {
#pragma unroll
    for (int ni = 0; ni < 4; ++ni) {
      int c = col0 + ni * 16 + l15;
      int rbase = row0 + w * (16 * MT) + mi * 16 + q * 4;
#pragma unroll
      for (int reg = 0; reg < 4; ++reg) {
        long row = rbase + reg;
        float v = acc[mi][ni][reg];
        if (EPI == 0) {
          C[row * ldc + c] = v;
          if (CS) cp[ni] += v;
        } else if (EPI == 3) {
          if (c < nvalid) {
            float t = v + bias[c];
            C[row * (long)nvalid + c] = t / (1.f + expf(-t));
          }
        } else if (EPI == 4) {
          float t = v + bias[c];
          t = 0.5f * t * (1.f + erf_apx(t * 0.70710678f));
          C2[row * ldc + c] = f2b(t);
        } else if (EPI == 5) {
          int bb = (int)(row / N_PIX); int p = (int)(row - (long)bb * N_PIX);
          float xsv = b2f(xs2[row * 256 + c]);
          float x2v = add[row * 256 + c] + g1v * xsv * sgv[row] * cgv[bb * 256 + c];
          float t = x2v + g2 * (v + bias[c]);
          C[((long)bb * 256 + c) * N_PIX + p] = t;
        } else if (EPI == 7) {
          float t = v + bias[c];
          C2[row * ldc + c] = f2b(t);
          if (CS) cp[ni] += t;
        }
      }
    }
  }
  if (CS) {
    int bb = (row0 >= N_PIX) ? 1 : 0;   // M=4608 grids only; boundary block-aligned
#pragma unroll
    for (int ni = 0; ni < 4; ++ni) {
      float r = cp[ni];
      r += __shfl_xor(r, 16);
      r += __shfl_xor(r, 32);
      if (lane < 16) atomicAdd(&cs_out[bb * cs_ld + col0 + ni * 16 + l15], r);
    }
  }
}

// ============ fused: topk-score (blocks 0..31) + depthwise 3x3 (32..4639) ===
__global__ __launch_bounds__(256) void tkdw_kernel(
    const float* __restrict__ qkv, const float* __restrict__ csum, int* __restrict__ out_idx,
    const float* __restrict__ xnhwc, const float* __restrict__ dw_w,
    const float* __restrict__ dw_b, u16* __restrict__ A2)
{
  __shared__ unsigned int u[N_PIX];
  __shared__ unsigned int hist[256];
  __shared__ unsigned int wtmp[4];
  __shared__ unsigned int sh_selbin, sh_selS;
  __shared__ unsigned int cnt_eq[4], cnt_sel[4];
  __shared__ float svl[32];
  int tid = threadIdx.x;
  if (blockIdx.x >= 32) {      // ---- depthwise conv part ----
    int pix = blockIdx.x - 32;
    int b = pix / N_PIX; int p = pix - b * N_PIX;
    int y = p / 48, xx = p - y * 48;
    int c = tid;
    float acc = dw_b[c];
#pragma unroll
    for (int ky = 0; ky < 3; ++ky) {
      int yy = y + ky - 1; if (yy < 0 || yy >= 48) continue;
#pragma unroll
      for (int kx = 0; kx < 3; ++kx) {
        int xc = xx + kx - 1; if (xc < 0 || xc >= 48) continue;
        acc += dw_w[c * 9 + ky * 3 + kx] * xnhwc[((long)(b * N_PIX + yy * 48 + xc)) * 256 + c];
      }
    }
    A2[(long)pix * 512 + 256 + c] = f2b(acc);
    return;
  }
  // ---- topk part ----
  int bh = blockIdx.x & 15, which = blockIdx.x >> 4;
  int b = bh >> 3, h = bh & 7;
  int* out = out_idx + (which * BHN + bh) * KTOP;
  int wave = tid >> 6, lane = tid & 63;
  unsigned long long ltmask = (1ull << lane) - 1ull;
  if (tid < 32) svl[tid] = csum[b * 768 + (which ? 0 : 256) + h * 32 + tid];
  __syncthreads();
  int off = (which ? 256 : 0) + h * 32;
  for (int i = tid; i < N_PIX; i += 256) {
    const float4* p4 = (const float4*)(qkv + ((long)(b * N_PIX + i)) * 768 + off);
    float sc = 0.f;
#pragma unroll
    for (int j = 0; j < 8; ++j) {
      float4 v = p4[j];
      sc += v.x * svl[j * 4] + v.y * svl[j * 4 + 1] + v.z * svl[j * 4 + 2] + v.w * svl[j * 4 + 3];
    }
    unsigned int bu = __float_as_uint(sc);
    u[i] = (bu & 0x80000000u) ? ~bu : (bu | 0x80000000u);
  }
  __syncthreads();
  unsigned int prefix = 0u, kRem = KTOP;
  for (int pass = 0; pass < 4; ++pass) {
    int shift = 24 - pass * 8;
    hist[tid] = 0u;
    __syncthreads();
    unsigned int mask = (pass == 0) ? 0u : (0xFFFFFFFFu << (shift + 8));
    for (int i = tid; i < N_PIX; i += 256) {
      unsigned int v = u[i];
      if ((v & mask) == prefix) atomicAdd(&hist[(v >> shift) & 255u], 1u);
    }
    __syncthreads();
    int v = (int)hist[255 - tid];
    int xsc = v;
#pragma unroll
    for (int o = 1; o < 64; o <<= 1) { int y = __shfl_up(xsc, o); if (lane >= o) xsc += y; }
    if (lane == 63) wtmp[wave] = (unsigned int)xsc;
    __syncthreads();
    int wadd = 0;
    for (int ww = 0; ww < wave; ++ww) wadd += (int)wtmp[ww];
    unsigned int S = (unsigned int)(xsc + wadd - v);
    if (S < kRem && S + (unsigned int)v >= kRem) { sh_selbin = (unsigned int)(255 - tid); sh_selS = S; }
    __syncthreads();
    prefix |= (sh_selbin << shift);
    kRem -= sh_selS;
    __syncthreads();
  }
  unsigned int T = prefix;
  unsigned int run_sel = 0u, run_eq = 0u;
  for (int c0 = 0; c0 < N_PIX; c0 += 256) {
    int i = c0 + tid;
    unsigned int v = u[i];
    bool isGt = v > T, isEq = (v == T);
    unsigned long long be = __ballot(isEq);
    unsigned int eqpre = (unsigned int)__popcll(be & ltmask);
    if (lane == 0) cnt_eq[wave] = (unsigned int)__popcll(be);
    __syncthreads();
    unsigned int eqoff = run_eq + eqpre;
    for (int ww = 0; ww < wave; ++ww) eqoff += cnt_eq[ww];
    bool selF = isGt || (isEq && eqoff < kRem);
    unsigned long long bs = __ballot(selF);
    unsigned int spre = (unsigned int)__popcll(bs & ltmask);
    if (lane == 0) cnt_sel[wave] = (unsigned int)__popcll(bs);
    __syncthreads();
    unsigned int soff = run_sel + spre;
    for (int ww = 0; ww < wave; ++ww) soff += cnt_sel[ww];
    if (selF) out[soff] = i;
    unsigned int te = 0, ts = 0;
#pragma unroll
    for (int ww = 0; ww < 4; ++ww) { te += cnt_eq[ww]; ts += cnt_sel[ww]; }
    run_eq += te; run_sel += ts;
    __syncthreads();
  }
}

// ============ gather kept rows/cols -> bf16 (+V col sums) + ofill into A2 ===
__global__ __launch_bounds__(256) void gather_kernel(
    const float* __restrict__ qkv, const int* __restrict__ idx,
    u16* __restrict__ Qg, u16* __restrict__ Kg, u16* __restrict__ VgT,
    float* __restrict__ vneg, const float* __restrict__ csum, u16* __restrict__ A2)
{
  __shared__ float red[256];
  int bh = blockIdx.y;
  int tid = threadIdx.x;
  int r = blockIdx.x * 8 + (tid >> 5);
  int d = tid & 31;
  int b = bh >> 3, h = bh & 7;
  int rn = idx[bh * KTOP + r];
  int cn = idx[(BHN + bh) * KTOP + r];
  const float scale = 0.17677669529663687f;    // 1/sqrt(32)
  float vv = qkv[((long)(b * N_PIX + cn)) * 768 + 512 + h * 32 + d];
  Qg [((long)bh * KTOP + r) * 32 + d] = f2b(qkv[((long)(b * N_PIX + rn)) * 768 + h * 32 + d] * scale);
  Kg [((long)bh * KTOP + r) * 32 + d] = f2b(qkv[((long)(b * N_PIX + cn)) * 768 + 256 + h * 32 + d]);
  VgT[((long)bh * 32 + d) * 584 + r] = f2b(vv);
  red[tid] = vv;
  // ---- ofill rows 4*bid..4*bid+3 with v_mean (attn overwrites kept rows)
  int bid = blockIdx.y * 72 + blockIdx.x;          // 0..1151
  int row = 4 * bid + (tid >> 6);
  int b2 = row / N_PIX;
  int c4 = (tid & 63) * 4;
  const float* vm = csum + b2 * 768 + 512 + c4;
  ushort4 ov;
  ov.x = f2b(vm[0] * (1.f / (float)N_PIX));
  ov.y = f2b(vm[1] * (1.f / (float)N_PIX));
  ov.z = f2b(vm[2] * (1.f / (float)N_PIX));
  ov.w = f2b(vm[3] * (1.f / (float)N_PIX));
  *(ushort4*)&A2[(long)row * 512 + c4] = ov;
  __syncthreads();
  if (tid < 32) {
    float s = 0.f;
#pragma unroll
    for (int j = 0; j < 8; ++j) s += red[j * 32 + tid];
    atomicAdd(&vneg[bh * 32 + tid], s);
  }
}

// ============ fused attention core: S=QK^T, softmax, E@V^T, scatter to A2 ===
__global__ __launch_bounds__(256) void attn_kernel(
    const u16* __restrict__ Qg, const u16* __restrict__ Kg, const u16* __restrict__ VgT,
    const float* __restrict__ csum, const float* __restrict__ vneg,
    const int* __restrict__ idx, u16* __restrict__ A2)
{
  __shared__ u16 Pls[32 * 584];
  __shared__ float wmax[4 * 32], wsum[4 * 32];
  __shared__ float emv_s[32], invd_s[32], vdif_s[32];
  int bh = blockIdx.y;
  int row0 = blockIdx.x * 32;
  int tid = threadIdx.x;
  int w = tid >> 6, lane = tid & 63;
  int q = lane >> 4, l15 = lane & 15;
  int b = bh >> 3, h = bh & 7;
  if (tid < 32) vdif_s[tid] = csum[b * 768 + 512 + h * 32 + tid] - vneg[bh * 32 + tid];
  const u16* Qb = Qg + (long)bh * KTOP * 32;
  const u16* Kb = Kg + (long)bh * KTOP * 32;
  short8v af[2];
#pragma unroll
  for (int mi = 0; mi < 2; ++mi)
    af[mi] = *(const short8v*)(Qb + ((long)(row0 + mi * 16 + l15)) * 32 + q * 8);
  floatx4 sacc[2][9];
#pragma unroll
  for (int mi = 0; mi < 2; ++mi)
#pragma unroll
    for (int ni = 0; ni < 9; ++ni) sacc[mi][ni] = (floatx4)0.f;
#pragma unroll
  for (int ni = 0; ni < 9; ++ni) {
    int n = w * 144 + ni * 16 + l15;
    short8v bf = *(const short8v*)(Kb + (long)n * 32 + q * 8);
#pragma unroll
    for (int mi = 0; mi < 2; ++mi)
      sacc[mi][ni] = __builtin_amdgcn_mfma_f32_16x16x32_bf16(af[mi], bf, sacc[mi][ni], 0, 0, 0);
  }
#pragma unroll
  for (int mi = 0; mi < 2; ++mi)
#pragma unroll
    for (int reg = 0; reg < 4; ++reg) {
      float m = sacc[mi][0][reg];
#pragma unroll
      for (int ni = 1; ni < 9; ++ni) m = fmaxf(m, sacc[mi][ni][reg]);
#pragma unroll
      for (int o = 1; o < 16; o <<= 1) m = fmaxf(m, __shfl_xor(m, o));
      if (l15 == 0) wmax[w * 32 + mi * 16 + q * 4 + reg] = m;
    }
  __syncthreads();
#pragma unroll
  for (int mi = 0; mi < 2; ++mi)
#pragma unroll
    for (int reg = 0; reg < 4; ++reg) {
      int r = mi * 16 + q * 4 + reg;
      float gm = fmaxf(fmaxf(fmaxf(wmax[r], wmax[32 + r]), fmaxf(wmax[64 + r], wmax[96 + r])), 0.f);
      float s = 0.f;
#pragma unroll
      for (int ni = 0; ni < 9; ++ni) {
        float e = expf(sacc[mi][ni][reg] - gm);
        s += e;
        Pls[r * 584 + w * 144 + ni * 16 + l15] = f2b(e);
      }
#pragma unroll
      for (int o = 1; o < 16; o <<= 1) s += __shfl_xor(s, o);
      if (l15 == 0) wsum[w * 32 + r] = s;
    }
  __syncthreads();
  if (tid < 32) {
    float gm = fmaxf(fmaxf(fmaxf(wmax[tid], wmax[32 + tid]), fmaxf(wmax[64 + tid], wmax[96 + tid])), 0.f);
    float s = wsum[tid] + wsum[32 + tid] + wsum[64 + tid] + wsum[96 + tid];
    float em = expf(-gm);
    float inv = 1.f / (s + (float)(N_PIX - KTOP) * em);
    invd_s[tid] = inv;
    emv_s[tid] = em * inv;
  }
  __syncthreads();
  int mw = w & 1, nw = w >> 1;
  const u16* Vb = VgT + (long)bh * 32 * 584;
  floatx4 acc = (floatx4)0.f;
#pragma unroll
  for (int kt = 0; kt < 18; ++kt) {
    int k0 = kt * 32;
    short8v a = *(const short8v*)&Pls[(mw * 16 + l15) * 584 + k0 + q * 8];
    short8v bb = *(const short8v*)(Vb + (long)(nw * 16 + l15) * 584 + k0 + q * 8);
    acc = __builtin_amdgcn_mfma_f32_16x16x32_bf16(a, bb, acc, 0, 0, 0);
  }
  int d = nw * 16 + l15;
  float vd = vdif_s[d];
#pragma unroll
  for (int reg = 0; reg < 4; ++reg) {
    int r = mw * 16 + q * 4 + reg;
    float o = acc[reg] * invd_s[r] + emv_s[r] * vd;
    int n = idx[bh * KTOP + row0 + r];
    A2[((long)(b * N_PIX + n)) * 512 + h * 32 + d] = f2b(o);
  }
}

// ============ fused spatial gate 7x7 (blocks 0..95) + channel MLP (96,97) ===
__global__ __launch_bounds__(256) void sgcg_kernel(
    const float* __restrict__ sga, const float* __restrict__ w,
    const float* __restrict__ b1, float* __restrict__ sgate,
    const float* __restrict__ cgm, const float* __restrict__ cw1, const float* __restrict__ cb1,
    const float* __restrict__ cw2, const float* __restrict__ cb2, float* __restrict__ cgate)
{
  __shared__ float ws[32 * 49];
  __shared__ float red[4 * 64];
  __shared__ float m[256];
  __shared__ float a[32];
  int t = threadIdx.x;
  if (blockIdx.x >= 96) {    // ---- channel-gate MLP ----
    int b = blockIdx.x - 96;
    m[t] = cgm[b * 256 + t] * (1.f / (float)N_PIX);
    __syncthreads();
    if (t < 32) {
      float s = cb1[t];
      for (int c = 0; c < 256; ++c) s += cw1[t * 256 + c] * m[c];
      a[t] = s / (1.f + expf(-s));
    }
    __syncthreads();
    float s = cb2[t];
#pragma unroll
    for (int g = 0; g < 32; ++g) s += cw2[t * 32 + g] * a[g];
    cgate[b * 256 + t] = 1.f / (1.f + expf(-s));
    return;
  }
  // ---- spatial gate ----
  int by = blockIdx.x; int b = by / 48, y = by - b * 48;
  for (int i = t; i < 32 * 49; i += 256) ws[i] = w[i];
  __syncthreads();
  int xx = t & 63, gg = t >> 6;
  float acc = 0.f;
  if (xx < 48) {
    for (int ky = 0; ky < 7; ++ky) {
      int yy = y + ky - 3; if (yy < 0 || yy >= 48) continue;
      for (int kx = 0; kx < 7; ++kx) {
        int xc = xx + kx - 3; if (xc < 0 || xc >= 48) continue;
        const float4* sp = (const float4*)(sga + ((long)(b * N_PIX + yy * 48 + xc)) * 32 + gg * 8);
        float4 v0 = sp[0], v1 = sp[1];
        int wb = gg * 8 * 49 + ky * 7 + kx;
        acc += ws[wb] * v0.x + ws[wb + 49] * v0.y + ws[wb + 98] * v0.z + ws[wb + 147] * v0.w;
        acc += ws[wb + 196] * v1.x + ws[wb + 245] * v1.y + ws[wb + 294] * v1.z + ws[wb + 343] * v1.w;
      }
    }
  }
  red[gg * 64 + xx] = acc;
  __syncthreads();
  if (t < 48) {
    float tot = b1[0] + red[t] + red[64 + t] + red[128 + t] + red[192 + t];
    sgate[b * N_PIX + y * 48 + t] = 1.f / (1.f + expf(-tot));
  }
}

// ============ gated LayerNorm2: v = x + g1*xs*sg*cg (not stored); LN -> bf16
__global__ __launch_bounds__(256) void gln_kernel(
    const float* __restrict__ xnhwc, const u16* __restrict__ xs_bf,
    const float* __restrict__ sgate, const float* __restrict__ cgate,
    const float* __restrict__ gamma1,
    const float* __restrict__ g, const float* __restrict__ bvec, u16* __restrict__ normed)
{
  __shared__ float red[256];
  int pix = blockIdx.x; int b = pix / N_PIX;
  int c = threadIdx.x;
  float xsv = b2f(xs_bf[(long)pix * 256 + c]);
  float v = xnhwc[(long)pix * 256 + c] + gamma1[0] * xsv * sgate[pix] * cgate[b * 256 + c];
  red[c] = v; __syncthreads();
  for (int off = 128; off > 0; off >>= 1) { if (c < off) red[c] += red[c + off]; __syncthreads(); }
  float mu = red[0] * (1.f / 256.f);
  __syncthreads();
  float dv = v - mu;
  red[c] = dv * dv; __syncthreads();
  for (int off = 128; off > 0; off >>= 1) { if (c < off) red[c] += red[c + off]; __syncthreads(); }
  float var = red[0] * (1.f / 256.f);
  normed[(long)pix * 256 + c] = f2b(dv * rsqrtf(var + 1e-6f) * g[c] + bvec[c]);
}

// ======================================================================
extern "C" void kernel_launch(void* const* d_in, const int* in_sizes, int n_in,
                              void* d_out, int out_size, void* d_ws, size_t ws_size,
                              hipStream_t stream) {
  (void)in_sizes; (void)n_in; (void)out_size; (void)ws_size;
  const float* x      = (const float*)d_in[0];
  const float* qkv_w  = (const float*)d_in[1];
  const float* out_w  = (const float*)d_in[2];
  const float* ln1_g  = (const float*)d_in[3];
  const float* ln1_b  = (const float*)d_in[4];
  const float* ln2_g  = (const float*)d_in[5];
  const float* ln2_b  = (const float*)d_in[6];
  const float* dw_w   = (const float*)d_in[7];
  const float* dw_b   = (const float*)d_in[8];
  const float* pw_w   = (const float*)d_in[9];
  const float* pw_b   = (const float*)d_in[10];
  const float* sg1_w  = (const float*)d_in[11];
  const float* sg1_b  = (const float*)d_in[12];
  const float* sg2_w  = (const float*)d_in[13];
  const float* sg2_b  = (const float*)d_in[14];
  const float* cg1_w  = (const float*)d_in[15];
  const float* cg1_b  = (const float*)d_in[16];
  const float* cg2_w  = (const float*)d_in[17];
  const float* cg2_b  = (const float*)d_in[18];
  const float* ff_w1  = (const float*)d_in[19];
  const float* ff_b1  = (const float*)d_in[20];
  const float* ff_w2  = (const float*)d_in[21];
  const float* ff_b2  = (const float*)d_in[22];
  const float* gamma1 = (const float*)d_in[23];
  const float* gamma2 = (const float*)d_in[24];
  float* out = (float*)d_out;
  float* ws  = (float*)d_ws;

  // -------- workspace layout (float units), total 8,130,048 fl = 32.5 MB ---
  float* qkv     = ws + 0;                  // 3,538,944 fp32; aliased h_bf / normed_bf
  u16*   A2      = (u16*)(ws + 3538944);    // 1,179,648 fl : [4608][512] bf16
  float* xnhwc   = ws + 4718592;            // 1,179,648
  u16*   xa_bf   = (u16*)(ws + 5898240);    // 589,824 fl
  u16*   xs_bf   = (u16*)(ws + 6488064);    // 589,824 fl
  u16*   Qg_bf   = (u16*)(ws + 7077888);    // 147,456 fl
  u16*   Kg_bf   = (u16*)(ws + 7225344);    // 147,456 fl
  u16*   VgT     = (u16*)(ws + 7372800);    // 149,504 fl  [16][32][584]
  float* sga     = ws + 7522304;            // 147,456
  float* csum    = ws + 7669760;            // 1,536  [2][768]  (zeroed by lncast blk 3536)
  float* vneg    = ws + 7671296;            // 512              (same zero block)
  float* cgm     = ws + 7671808;            // 512              (same zero block)
  float* sgate   = ws + 7672320;            // 4,608
  float* cgate   = ws + 7676928;            // 512
  int*   idxb    = (int*)(ws + 7677440);    // 18,432 ints
  u16*   qkvBT   = (u16*)(ws + 7695872);    // 98,304 fl
  u16*   B2combo = (u16*)(ws + 7794176);    // 65,536 fl : [256][512]
  u16*   ff1BT   = (u16*)(ws + 7859712);    // 131,072 fl
  u16*   ff2BT   = (u16*)(ws + 7990784);    // 131,072 fl
  u16*   sg1BT   = (u16*)(ws + 8121856);    // 8,192 fl -> end 8,130,048
  // aliases of qkv region (qkv fp32 dead after gather):
  u16*   h_bf     = (u16*)qkv;              // [0, 2,359,296) fl
  u16*   normed_bf= (u16*)(ws + 2359296);   // [2,359,296, 2,949,120) fl

  dim3 blk(256);

  // ---- ln1 + weight casts + scratch zeroing (fused) ----
  lncast_kernel<<<dim3(3537), blk, 0, stream>>>(x, xa_bf, xnhwc, ln1_g, ln1_b,
      qkv_w, out_w, pw_w, ff_w1, ff_w2, sg1_w,
      qkvBT, B2combo, ff1BT, ff2BT, sg1BT, csum);

  // ---- attention branch ----
  dgemm<2, 0, 1><<<dim3(12, 36), blk, 0, stream>>>(xa_bf, qkvBT, qkv, nullptr,
      256, 768, 768, nullptr, nullptr, nullptr, csum, 768, nullptr, nullptr, nullptr, nullptr);
  tkdw_kernel<<<dim3(4640), blk, 0, stream>>>(qkv, csum, idxb, xnhwc, dw_w, dw_b, A2);
  gather_kernel<<<dim3(72, BHN), blk, 0, stream>>>(qkv, idxb, Qg_bf, Kg_bf, VgT, vneg,
      csum, A2);
  attn_kernel<<<dim3(18, BHN), blk, 0, stream>>>(Qg_bf, Kg_bf, VgT, csum, vneg, idxb, A2);

  // ---- merged xs = [attn|dwc] @ B2 + pw_b  (K=512) ----
  dgemm<1, 7, 1><<<dim3(4, 72), blk, 0, stream>>>(A2, B2combo, nullptr, xs_bf,
      512, 256, 256, pw_b, nullptr, nullptr, cgm, 256, nullptr, nullptr, nullptr, nullptr);

  // ---- gates ----
  dgemm<1, 3, 0><<<dim3(1, 72), blk, 0, stream>>>(xs_bf, sg1BT, sga, nullptr,
      256, 32, 32, sg1_b, nullptr, nullptr, nullptr, 0, nullptr, nullptr, nullptr, nullptr);
  sgcg_kernel<<<dim3(98), blk, 0, stream>>>(sga, sg2_w, sg2_b, sgate,
      cgm, cg1_w, cg1_b, cg2_w, cg2_b, cgate);

  // ---- LN2 (x2 recomputed, not stored) ----
  gln_kernel<<<dim3(NROWS), blk, 0, stream>>>(xnhwc, xs_bf, sgate, cgate, gamma1,
      ln2_g, ln2_b, normed_bf);

  // ---- FFN ----
  dgemm<2, 4, 0><<<dim3(16, 36), blk, 0, stream>>>(normed_bf, ff1BT, nullptr, h_bf,
      256, 1024, 1024, ff_b1, nullptr, nullptr, nullptr, 0, nullptr, nullptr, nullptr, nullptr);
  dgemm<1, 5, 0><<<dim3(4, 72), blk, 0, stream>>>(h_bf, ff2BT, out, nullptr,
      1024, 256, 256, ff_b2, xnhwc, gamma2, nullptr, 0, xs_bf, sgate, cgate, gamma1);
}

// Round 12
// 246.739 us; speedup vs baseline: 1.1732x; 1.1732x over previous
//
#include <hip/hip_runtime.h>
#include <math.h>

#define N_PIX 2304
#define CCH   256
#define BHN   16     // B * NHEAD
#define KTOP  576
#define NROWS 4608   // B * N_PIX

typedef unsigned short u16;
typedef __attribute__((ext_vector_type(8))) short short8v;   // 8 bf16
typedef __attribute__((ext_vector_type(4))) float floatx4;

__device__ __forceinline__ u16 f2b(float f) {
  unsigned int u = __float_as_uint(f);
  return (u16)((u + 0x7fffu + ((u >> 16) & 1u)) >> 16);      // RNE
}
__device__ __forceinline__ float b2f(u16 v) {
  return __uint_as_float(((unsigned int)v) << 16);
}

// NOTE (m104/m108): LDS dest of global_load_lds is wave-uniform base + lane*16.
__device__ __forceinline__ void async16(const void* g, void* l) {
  __builtin_amdgcn_global_load_lds(
      (const __attribute__((address_space(1))) unsigned int*)g,
      (__attribute__((address_space(3))) unsigned int*)l, 16, 0, 0);
}

// float-only erf (A&S 7.1.26, |err|<=1.5e-7)
__device__ __forceinline__ float erf_apx(float x) {
  float ax = fabsf(x);
  float u = 1.f / (1.f + 0.3275911f * ax);
  float y = u * (0.254829592f + u * (-0.284496736f + u * (1.421413741f +
            u * (-1.453152027f + u * 1.061405429f))));
  float r = 1.f - y * expf(-ax * ax);
  return (x < 0.f) ? -r : r;
}

// ============ fused: ln1 (blocks 0..143) + weight casts (144..3535) + zero (3536)
// B2 combo: B2[n][k<256] = out_w[k][n] ; B2[n][256+i] = pw_w[n][i]
__global__ __launch_bounds__(256) void lncast_kernel(
    const float* __restrict__ x, u16* __restrict__ xa_bf, float* __restrict__ xnhwc,
    const float* __restrict__ g, const float* __restrict__ beta,
    const float* __restrict__ qkv_w, const float* __restrict__ out_w,
    const float* __restrict__ pw_w, const float* __restrict__ ff_w1,
    const float* __restrict__ ff_w2, const float* __restrict__ sg1_w,
    u16* __restrict__ qkvBT, u16* __restrict__ B2,
    u16* __restrict__ ff1BT, u16* __restrict__ ff2BT, u16* __restrict__ sg1BT,
    float* __restrict__ zbuf)
{
  __shared__ float tile[32 * 257];
  __shared__ float redS[8 * 32], redQ[8 * 32];
  __shared__ float mu_s[32], rs_s[32];
  int tid = threadIdx.x;
  if (blockIdx.x == 3536) {     // ---- zero csum/vneg/cgm ----
#pragma unroll
    for (int j = 0; j < 10; ++j) zbuf[tid + j * 256] = 0.f;
    return;
  }
  if (blockIdx.x >= 144) {      // ---- weight-cast part ----
    int i = (blockIdx.x - 144) * 256 + tid;
    if (i < 196608) { int k = i / 768, n = i - k * 768; qkvBT[n * 256 + k] = f2b(qkv_w[i]); return; }
    i -= 196608;
    if (i < 65536) { int k = i >> 8, n = i & 255; B2[n * 512 + k] = f2b(out_w[i]); return; }
    i -= 65536;
    if (i < 65536) { int n = i >> 8, ic = i & 255; B2[n * 512 + 256 + ic] = f2b(pw_w[i]); return; }
    i -= 65536;
    if (i < 262144) { int k = i >> 10, n = i & 1023; ff1BT[n * 256 + k] = f2b(ff_w1[i]); return; }
    i -= 262144;
    if (i < 262144) { int k = i & 1023, n = i >> 10; ff2BT[i] = f2b(ff_w2[k * 256 + n]); return; }
    i -= 262144;
    if (i < 16384) sg1BT[i] = (i < 8192) ? f2b(sg1_w[i]) : (u16)0;
    return;
  }
  // ---- ln1 part ----
  int p0g = blockIdx.x * 32;
  int bb = p0g / N_PIX; int p0 = p0g - bb * N_PIX;
  int px = tid & 31, csub = tid >> 5;
  float sacc = 0.f, qacc = 0.f;
#pragma unroll 4
  for (int it = 0; it < 32; ++it) {
    int c = it * 8 + csub;
    float v = x[((long)bb * 256 + c) * N_PIX + p0 + px];
    tile[px * 257 + c] = v;
    sacc += v; qacc += v * v;
  }
  redS[csub * 32 + px] = sacc; redQ[csub * 32 + px] = qacc;
  __syncthreads();
  if (tid < 32) {
    float s = 0.f, qq = 0.f;
#pragma unroll
    for (int j = 0; j < 8; ++j) { s += redS[j * 32 + tid]; qq += redQ[j * 32 + tid]; }
    float mu = s * (1.f / 256.f);
    float var = qq * (1.f / 256.f) - mu * mu;
    mu_s[tid] = mu; rs_s[tid] = rsqrtf(var + 1e-6f);
  }
  __syncthreads();
  float gv = g[tid], bv = beta[tid];
#pragma unroll 4
  for (int it = 0; it < 32; ++it) {
    float v = tile[it * 257 + tid];
    long orow = (long)(p0g + it) * 256 + tid;
    xnhwc[orow] = v;
    xa_bf[orow] = f2b((v - mu_s[it]) * rs_s[it] * gv + bv);
  }
}

// ============ bf16 MFMA GEMM (LDS-staged): tile (MT*64)x64, BK=32 =====
// EPI 0: C fp32 = acc                      (CS: col-sums -> cs_out)
// EPI 3: silu(acc+bias) -> C fp32, cols < nvalid
// EPI 4: gelu(acc+bias) -> C2 bf16
// EPI 5: out NCHW = [xnhwc + g1*xs*sg*cg](recomputed x2) + gamma*(acc+bias)
// EPI 7: acc+bias -> C2 bf16               (CS: col-sums)
template<int MT, int EPI, int CS>
__global__ __launch_bounds__(256) void mgemm(
    const u16* __restrict__ A, const u16* __restrict__ BT,
    float* __restrict__ C, u16* __restrict__ C2,
    int K, int ldc, int nvalid,
    const float* __restrict__ bias, const float* __restrict__ add,
    const float* __restrict__ gamma,
    float* __restrict__ cs_out, int cs_ld,
    const u16* __restrict__ xs2, const float* __restrict__ sgv,
    const float* __restrict__ cgv, const float* __restrict__ g1p)
{
  __shared__ u16 Als[MT * 64 * 32];
  __shared__ u16 Bls[64 * 32];
  int tid = threadIdx.x;
  int w = tid >> 6, lane = tid & 63;
  int row0 = blockIdx.y * (MT * 64), col0 = blockIdx.x * 64;
  const u16* Abase = A + (long)row0 * K;
  const u16* Bbase = BT + (long)col0 * K;
  int q = lane >> 4, l15 = lane & 15;

  floatx4 acc[MT][4];
#pragma unroll
  for (int mi = 0; mi < MT; ++mi)
#pragma unroll
    for (int ni = 0; ni < 4; ++ni) acc[mi][ni] = (floatx4)0.f;

  int ccB = w * 64 + lane;
  int rB = ccB >> 2, kB = (ccB & 3) << 3;

  for (int k0 = 0; k0 < K; k0 += 32) {
#pragma unroll
    for (int i = 0; i < MT; ++i) {
      int cc = w * (64 * MT) + i * 64 + lane;
      async16(Abase + (long)(cc >> 2) * K + k0 + ((cc & 3) << 3), &Als[cc * 8]);
    }
    async16(Bbase + (long)rB * K + k0 + kB, &Bls[ccB * 8]);
    __syncthreads();
    short8v a[MT];
#pragma unroll
    for (int mi = 0; mi < MT; ++mi)
      a[mi] = *(const short8v*)&Als[(w * (16 * MT) + mi * 16 + l15) * 32 + q * 8];
#pragma unroll
    for (int ni = 0; ni < 4; ++ni) {
      short8v b = *(const short8v*)&Bls[(ni * 16 + l15) * 32 + q * 8];
#pragma unroll
      for (int mi = 0; mi < MT; ++mi)
        acc[mi][ni] = __builtin_amdgcn_mfma_f32_16x16x32_bf16(a[mi], b, acc[mi][ni], 0, 0, 0);
    }
    __syncthreads();
  }

  float g2 = (EPI == 5) ? gamma[0] : 0.f;
  float g1v = (EPI == 5) ? g1p[0] : 0.f;
  float cp[4] = {0.f, 0.f, 0.f, 0.f};
#pragma unroll
  for (int mi = 0; mi < MT; ++mi) {
#pragma unroll
    for (int ni = 0; ni < 4; ++ni) {
      int c = col0 + ni * 16 + l15;
      int rbase = row0 + w * (16 * MT) + mi * 16 + q * 4;
#pragma unroll
      for (int reg = 0; reg < 4; ++reg) {
        long row = rbase + reg;
        float v = acc[mi][ni][reg];
        if (EPI == 0) {
          C[row * ldc + c] = v;
          if (CS) cp[ni] += v;
        } else if (EPI == 3) {
          if (c < nvalid) {
            float t = v + bias[c];
            C[row * (long)nvalid + c] = t / (1.f + expf(-t));
          }
        } else if (EPI == 4) {
          float t = v + bias[c];
          t = 0.5f * t * (1.f + erf_apx(t * 0.70710678f));
          C2[row * ldc + c] = f2b(t);
        } else if (EPI == 5) {
          int bb = (int)(row / N_PIX); int p = (int)(row - (long)bb * N_PIX);
          float xsv = b2f(xs2[row * 256 + c]);
          float x2v = add[row * 256 + c] + g1v * xsv * sgv[row] * cgv[bb * 256 + c];
          float t = x2v + g2 * (v + bias[c]);
          C[((long)bb * 256 + c) * N_PIX + p] = t;
        } else if (EPI == 7) {
          float t = v + bias[c];
          C2[row * ldc + c] = f2b(t);
          if (CS) cp[ni] += t;
        }
      }
    }
  }
  if (CS) {
    int bb = (row0 >= N_PIX) ? 1 : 0;   // M=4608 grids only; boundary block-aligned
#pragma unroll
    for (int ni = 0; ni < 4; ++ni) {
      float r = cp[ni];
      r += __shfl_xor(r, 16);
      r += __shfl_xor(r, 32);
      if (lane < 16) atomicAdd(&cs_out[bb * cs_ld + col0 + ni * 16 + l15], r);
    }
  }
}

// ============ fused: topk-score (blocks 0..31) + depthwise 3x3 (32..4639) ===
__global__ __launch_bounds__(256) void tkdw_kernel(
    const float* __restrict__ qkv, const float* __restrict__ csum, int* __restrict__ out_idx,
    const float* __restrict__ xnhwc, const float* __restrict__ dw_w,
    const float* __restrict__ dw_b, u16* __restrict__ A2)
{
  __shared__ unsigned int u[N_PIX];
  __shared__ unsigned int hist[256];
  __shared__ unsigned int wtmp[4];
  __shared__ unsigned int sh_selbin, sh_selS;
  __shared__ unsigned int cnt_eq[4], cnt_sel[4];
  __shared__ float svl[32];
  int tid = threadIdx.x;
  if (blockIdx.x >= 32) {      // ---- depthwise conv part ----
    int pix = blockIdx.x - 32;
    int b = pix / N_PIX; int p = pix - b * N_PIX;
    int y = p / 48, xx = p - y * 48;
    int c = tid;
    float acc = dw_b[c];
#pragma unroll
    for (int ky = 0; ky < 3; ++ky) {
      int yy = y + ky - 1; if (yy < 0 || yy >= 48) continue;
#pragma unroll
      for (int kx = 0; kx < 3; ++kx) {
        int xc = xx + kx - 1; if (xc < 0 || xc >= 48) continue;
        acc += dw_w[c * 9 + ky * 3 + kx] * xnhwc[((long)(b * N_PIX + yy * 48 + xc)) * 256 + c];
      }
    }
    A2[(long)pix * 512 + 256 + c] = f2b(acc);
    return;
  }
  // ---- topk part ----
  int bh = blockIdx.x & 15, which = blockIdx.x >> 4;
  int b = bh >> 3, h = bh & 7;
  int* out = out_idx + (which * BHN + bh) * KTOP;
  int wave = tid >> 6, lane = tid & 63;
  unsigned long long ltmask = (1ull << lane) - 1ull;
  if (tid < 32) svl[tid] = csum[b * 768 + (which ? 0 : 256) + h * 32 + tid];
  __syncthreads();
  int off = (which ? 256 : 0) + h * 32;
  for (int i = tid; i < N_PIX; i += 256) {
    const float4* p4 = (const float4*)(qkv + ((long)(b * N_PIX + i)) * 768 + off);
    float sc = 0.f;
#pragma unroll
    for (int j = 0; j < 8; ++j) {
      float4 v = p4[j];
      sc += v.x * svl[j * 4] + v.y * svl[j * 4 + 1] + v.z * svl[j * 4 + 2] + v.w * svl[j * 4 + 3];
    }
    unsigned int bu = __float_as_uint(sc);
    u[i] = (bu & 0x80000000u) ? ~bu : (bu | 0x80000000u);
  }
  __syncthreads();
  unsigned int prefix = 0u, kRem = KTOP;
  for (int pass = 0; pass < 4; ++pass) {
    int shift = 24 - pass * 8;
    hist[tid] = 0u;
    __syncthreads();
    unsigned int mask = (pass == 0) ? 0u : (0xFFFFFFFFu << (shift + 8));
    for (int i = tid; i < N_PIX; i += 256) {
      unsigned int v = u[i];
      if ((v & mask) == prefix) atomicAdd(&hist[(v >> shift) & 255u], 1u);
    }
    __syncthreads();
    int v = (int)hist[255 - tid];
    int xsc = v;
#pragma unroll
    for (int o = 1; o < 64; o <<= 1) { int y = __shfl_up(xsc, o); if (lane >= o) xsc += y; }
    if (lane == 63) wtmp[wave] = (unsigned int)xsc;
    __syncthreads();
    int wadd = 0;
    for (int ww = 0; ww < wave; ++ww) wadd += (int)wtmp[ww];
    unsigned int S = (unsigned int)(xsc + wadd - v);
    if (S < kRem && S + (unsigned int)v >= kRem) { sh_selbin = (unsigned int)(255 - tid); sh_selS = S; }
    __syncthreads();
    prefix |= (sh_selbin << shift);
    kRem -= sh_selS;
    __syncthreads();
  }
  unsigned int T = prefix;
  unsigned int run_sel = 0u, run_eq = 0u;
  for (int c0 = 0; c0 < N_PIX; c0 += 256) {
    int i = c0 + tid;
    unsigned int v = u[i];
    bool isGt = v > T, isEq = (v == T);
    unsigned long long be = __ballot(isEq);
    unsigned int eqpre = (unsigned int)__popcll(be & ltmask);
    if (lane == 0) cnt_eq[wave] = (unsigned int)__popcll(be);
    __syncthreads();
    unsigned int eqoff = run_eq + eqpre;
    for (int ww = 0; ww < wave; ++ww) eqoff += cnt_eq[ww];
    bool selF = isGt || (isEq && eqoff < kRem);
    unsigned long long bs = __ballot(selF);
    unsigned int spre = (unsigned int)__popcll(bs & ltmask);
    if (lane == 0) cnt_sel[wave] = (unsigned int)__popcll(bs);
    __syncthreads();
    unsigned int soff = run_sel + spre;
    for (int ww = 0; ww < wave; ++ww) soff += cnt_sel[ww];
    if (selF) out[soff] = i;
    unsigned int te = 0, ts = 0;
#pragma unroll
    for (int ww = 0; ww < 4; ++ww) { te += cnt_eq[ww]; ts += cnt_sel[ww]; }
    run_eq += te; run_sel += ts;
    __syncthreads();
  }
}

// ============ gather kept rows/cols -> bf16 (+V col sums) + ofill into A2 ===
__global__ __launch_bounds__(256) void gather_kernel(
    const float* __restrict__ qkv, const int* __restrict__ idx,
    u16* __restrict__ Qg, u16* __restrict__ Kg, u16* __restrict__ VgT,
    float* __restrict__ vneg, const float* __restrict__ csum, u16* __restrict__ A2)
{
  __shared__ float red[256];
  int bh = blockIdx.y;
  int tid = threadIdx.x;
  int r = blockIdx.x * 8 + (tid >> 5);
  int d = tid & 31;
  int b = bh >> 3, h = bh & 7;
  int rn = idx[bh * KTOP + r];
  int cn = idx[(BHN + bh) * KTOP + r];
  const float scale = 0.17677669529663687f;    // 1/sqrt(32)
  float vv = qkv[((long)(b * N_PIX + cn)) * 768 + 512 + h * 32 + d];
  Qg [((long)bh * KTOP + r) * 32 + d] = f2b(qkv[((long)(b * N_PIX + rn)) * 768 + h * 32 + d] * scale);
  Kg [((long)bh * KTOP + r) * 32 + d] = f2b(qkv[((long)(b * N_PIX + cn)) * 768 + 256 + h * 32 + d]);
  VgT[((long)bh * 32 + d) * 584 + r] = f2b(vv);
  red[tid] = vv;
  // ---- ofill rows 4*bid..4*bid+3 with v_mean (attn overwrites kept rows)
  int bid = blockIdx.y * 72 + blockIdx.x;          // 0..1151
  int row = 4 * bid + (tid >> 6);
  int b2 = row / N_PIX;
  int c4 = (tid & 63) * 4;
  const float* vm = csum + b2 * 768 + 512 + c4;
  ushort4 ov;
  ov.x = f2b(vm[0] * (1.f / (float)N_PIX));
  ov.y = f2b(vm[1] * (1.f / (float)N_PIX));
  ov.z = f2b(vm[2] * (1.f / (float)N_PIX));
  ov.w = f2b(vm[3] * (1.f / (float)N_PIX));
  *(ushort4*)&A2[(long)row * 512 + c4] = ov;
  __syncthreads();
  if (tid < 32) {
    float s = 0.f;
#pragma unroll
    for (int j = 0; j < 8; ++j) s += red[j * 32 + tid];
    atomicAdd(&vneg[bh * 32 + tid], s);
  }
}

// ============ fused attention core: S=QK^T, softmax, E@V^T, scatter to A2 ===
__global__ __launch_bounds__(256) void attn_kernel(
    const u16* __restrict__ Qg, const u16* __restrict__ Kg, const u16* __restrict__ VgT,
    const float* __restrict__ csum, const float* __restrict__ vneg,
    const int* __restrict__ idx, u16* __restrict__ A2)
{
  __shared__ u16 Pls[32 * 584];
  __shared__ float wmax[4 * 32], wsum[4 * 32];
  __shared__ float emv_s[32], invd_s[32], vdif_s[32];
  int bh = blockIdx.y;
  int row0 = blockIdx.x * 32;
  int tid = threadIdx.x;
  int w = tid >> 6, lane = tid & 63;
  int q = lane >> 4, l15 = lane & 15;
  int b = bh >> 3, h = bh & 7;
  if (tid < 32) vdif_s[tid] = csum[b * 768 + 512 + h * 32 + tid] - vneg[bh * 32 + tid];
  const u16* Qb = Qg + (long)bh * KTOP * 32;
  const u16* Kb = Kg + (long)bh * KTOP * 32;
  short8v af[2];
#pragma unroll
  for (int mi = 0; mi < 2; ++mi)
    af[mi] = *(const short8v*)(Qb + ((long)(row0 + mi * 16 + l15)) * 32 + q * 8);
  floatx4 sacc[2][9];
#pragma unroll
  for (int mi = 0; mi < 2; ++mi)
#pragma unroll
    for (int ni = 0; ni < 9; ++ni) sacc[mi][ni] = (floatx4)0.f;
#pragma unroll
  for (int ni = 0; ni < 9; ++ni) {
    int n = w * 144 + ni * 16 + l15;
    short8v bf = *(const short8v*)(Kb + (long)n * 32 + q * 8);
#pragma unroll
    for (int mi = 0; mi < 2; ++mi)
      sacc[mi][ni] = __builtin_amdgcn_mfma_f32_16x16x32_bf16(af[mi], bf, sacc[mi][ni], 0, 0, 0);
  }
#pragma unroll
  for (int mi = 0; mi < 2; ++mi)
#pragma unroll
    for (int reg = 0; reg < 4; ++reg) {
      float m = sacc[mi][0][reg];
#pragma unroll
      for (int ni = 1; ni < 9; ++ni) m = fmaxf(m, sacc[mi][ni][reg]);
#pragma unroll
      for (int o = 1; o < 16; o <<= 1) m = fmaxf(m, __shfl_xor(m, o));
      if (l15 == 0) wmax[w * 32 + mi * 16 + q * 4 + reg] = m;
    }
  __syncthreads();
#pragma unroll
  for (int mi = 0; mi < 2; ++mi)
#pragma unroll
    for (int reg = 0; reg < 4; ++reg) {
      int r = mi * 16 + q * 4 + reg;
      float gm = fmaxf(fmaxf(fmaxf(wmax[r], wmax[32 + r]), fmaxf(wmax[64 + r], wmax[96 + r])), 0.f);
      float s = 0.f;
#pragma unroll
      for (int ni = 0; ni < 9; ++ni) {
        float e = expf(sacc[mi][ni][reg] - gm);
        s += e;
        Pls[r * 584 + w * 144 + ni * 16 + l15] = f2b(e);
      }
#pragma unroll
      for (int o = 1; o < 16; o <<= 1) s += __shfl_xor(s, o);
      if (l15 == 0) wsum[w * 32 + r] = s;
    }
  __syncthreads();
  if (tid < 32) {
    float gm = fmaxf(fmaxf(fmaxf(wmax[tid], wmax[32 + tid]), fmaxf(wmax[64 + tid], wmax[96 + tid])), 0.f);
    float s = wsum[tid] + wsum[32 + tid] + wsum[64 + tid] + wsum[96 + tid];
    float em = expf(-gm);
    float inv = 1.f / (s + (float)(N_PIX - KTOP) * em);
    invd_s[tid] = inv;
    emv_s[tid] = em * inv;
  }
  __syncthreads();
  int mw = w & 1, nw = w >> 1;
  const u16* Vb = VgT + (long)bh * 32 * 584;
  floatx4 acc = (floatx4)0.f;
#pragma unroll
  for (int kt = 0; kt < 18; ++kt) {
    int k0 = kt * 32;
    short8v a = *(const short8v*)&Pls[(mw * 16 + l15) * 584 + k0 + q * 8];
    short8v bb = *(const short8v*)(Vb + (long)(nw * 16 + l15) * 584 + k0 + q * 8);
    acc = __builtin_amdgcn_mfma_f32_16x16x32_bf16(a, bb, acc, 0, 0, 0);
  }
  int d = nw * 16 + l15;
  float vd = vdif_s[d];
#pragma unroll
  for (int reg = 0; reg < 4; ++reg) {
    int r = mw * 16 + q * 4 + reg;
    float o = acc[reg] * invd_s[r] + emv_s[r] * vd;
    int n = idx[bh * KTOP + row0 + r];
    A2[((long)(b * N_PIX + n)) * 512 + h * 32 + d] = f2b(o);
  }
}

// ============ fused spatial gate 7x7 (blocks 0..95) + channel MLP (96,97) ===
__global__ __launch_bounds__(256) void sgcg_kernel(
    const float* __restrict__ sga, const float* __restrict__ w,
    const float* __restrict__ b1, float* __restrict__ sgate,
    const float* __restrict__ cgm, const float* __restrict__ cw1, const float* __restrict__ cb1,
    const float* __restrict__ cw2, const float* __restrict__ cb2, float* __restrict__ cgate)
{
  __shared__ float ws[32 * 49];
  __shared__ float red[4 * 64];
  __shared__ float m[256];
  __shared__ float a[32];
  int t = threadIdx.x;
  if (blockIdx.x >= 96) {    // ---- channel-gate MLP ----
    int b = blockIdx.x - 96;
    m[t] = cgm[b * 256 + t] * (1.f / (float)N_PIX);
    __syncthreads();
    if (t < 32) {
      float s = cb1[t];
      for (int c = 0; c < 256; ++c) s += cw1[t * 256 + c] * m[c];
      a[t] = s / (1.f + expf(-s));
    }
    __syncthreads();
    float s = cb2[t];
#pragma unroll
    for (int g = 0; g < 32; ++g) s += cw2[t * 32 + g] * a[g];
    cgate[b * 256 + t] = 1.f / (1.f + expf(-s));
    return;
  }
  // ---- spatial gate ----
  int by = blockIdx.x; int b = by / 48, y = by - b * 48;
  for (int i = t; i < 32 * 49; i += 256) ws[i] = w[i];
  __syncthreads();
  int xx = t & 63, gg = t >> 6;
  float acc = 0.f;
  if (xx < 48) {
    for (int ky = 0; ky < 7; ++ky) {
      int yy = y + ky - 3; if (yy < 0 || yy >= 48) continue;
      for (int kx = 0; kx < 7; ++kx) {
        int xc = xx + kx - 3; if (xc < 0 || xc >= 48) continue;
        const float4* sp = (const float4*)(sga + ((long)(b * N_PIX + yy * 48 + xc)) * 32 + gg * 8);
        float4 v0 = sp[0], v1 = sp[1];
        int wb = gg * 8 * 49 + ky * 7 + kx;
        acc += ws[wb] * v0.x + ws[wb + 49] * v0.y + ws[wb + 98] * v0.z + ws[wb + 147] * v0.w;
        acc += ws[wb + 196] * v1.x + ws[wb + 245] * v1.y + ws[wb + 294] * v1.z + ws[wb + 343] * v1.w;
      }
    }
  }
  red[gg * 64 + xx] = acc;
  __syncthreads();
  if (t < 48) {
    float tot = b1[0] + red[t] + red[64 + t] + red[128 + t] + red[192 + t];
    sgate[b * N_PIX + y * 48 + t] = 1.f / (1.f + expf(-tot));
  }
}

// ============ gated LayerNorm2: v = x + g1*xs*sg*cg (not stored); LN -> bf16
__global__ __launch_bounds__(256) void gln_kernel(
    const float* __restrict__ xnhwc, const u16* __restrict__ xs_bf,
    const float* __restrict__ sgate, const float* __restrict__ cgate,
    const float* __restrict__ gamma1,
    const float* __restrict__ g, const float* __restrict__ bvec, u16* __restrict__ normed)
{
  __shared__ float red[256];
  int pix = blockIdx.x; int b = pix / N_PIX;
  int c = threadIdx.x;
  float xsv = b2f(xs_bf[(long)pix * 256 + c]);
  float v = xnhwc[(long)pix * 256 + c] + gamma1[0] * xsv * sgate[pix] * cgate[b * 256 + c];
  red[c] = v; __syncthreads();
  for (int off = 128; off > 0; off >>= 1) { if (c < off) red[c] += red[c + off]; __syncthreads(); }
  float mu = red[0] * (1.f / 256.f);
  __syncthreads();
  float dv = v - mu;
  red[c] = dv * dv; __syncthreads();
  for (int off = 128; off > 0; off >>= 1) { if (c < off) red[c] += red[c + off]; __syncthreads(); }
  float var = red[0] * (1.f / 256.f);
  normed[(long)pix * 256 + c] = f2b(dv * rsqrtf(var + 1e-6f) * g[c] + bvec[c]);
}

// ======================================================================
extern "C" void kernel_launch(void* const* d_in, const int* in_sizes, int n_in,
                              void* d_out, int out_size, void* d_ws, size_t ws_size,
                              hipStream_t stream) {
  (void)in_sizes; (void)n_in; (void)out_size; (void)ws_size;
  const float* x      = (const float*)d_in[0];
  const float* qkv_w  = (const float*)d_in[1];
  const float* out_w  = (const float*)d_in[2];
  const float* ln1_g  = (const float*)d_in[3];
  const float* ln1_b  = (const float*)d_in[4];
  const float* ln2_g  = (const float*)d_in[5];
  const float* ln2_b  = (const float*)d_in[6];
  const float* dw_w   = (const float*)d_in[7];
  const float* dw_b   = (const float*)d_in[8];
  const float* pw_w   = (const float*)d_in[9];
  const float* pw_b   = (const float*)d_in[10];
  const float* sg1_w  = (const float*)d_in[11];
  const float* sg1_b  = (const float*)d_in[12];
  const float* sg2_w  = (const float*)d_in[13];
  const float* sg2_b  = (const float*)d_in[14];
  const float* cg1_w  = (const float*)d_in[15];
  const float* cg1_b  = (const float*)d_in[16];
  const float* cg2_w  = (const float*)d_in[17];
  const float* cg2_b  = (const float*)d_in[18];
  const float* ff_w1  = (const float*)d_in[19];
  const float* ff_b1  = (const float*)d_in[20];
  const float* ff_w2  = (const float*)d_in[21];
  const float* ff_b2  = (const float*)d_in[22];
  const float* gamma1 = (const float*)d_in[23];
  const float* gamma2 = (const float*)d_in[24];
  float* out = (float*)d_out;
  float* ws  = (float*)d_ws;

  // -------- workspace layout (float units), total 8,130,048 fl = 32.5 MB ---
  float* qkv     = ws + 0;                  // 3,538,944 fp32; aliased h_bf / normed_bf
  u16*   A2      = (u16*)(ws + 3538944);    // 1,179,648 fl : [4608][512] bf16
  float* xnhwc   = ws + 4718592;            // 1,179,648
  u16*   xa_bf   = (u16*)(ws + 5898240);    // 589,824 fl
  u16*   xs_bf   = (u16*)(ws + 6488064);    // 589,824 fl
  u16*   Qg_bf   = (u16*)(ws + 7077888);    // 147,456 fl
  u16*   Kg_bf   = (u16*)(ws + 7225344);    // 147,456 fl
  u16*   VgT     = (u16*)(ws + 7372800);    // 149,504 fl  [16][32][584]
  float* sga     = ws + 7522304;            // 147,456
  float* csum    = ws + 7669760;            // 1,536  [2][768]  (zeroed by lncast blk 3536)
  float* vneg    = ws + 7671296;            // 512              (same zero block)
  float* cgm     = ws + 7671808;            // 512              (same zero block)
  float* sgate   = ws + 7672320;            // 4,608
  float* cgate   = ws + 7676928;            // 512
  int*   idxb    = (int*)(ws + 7677440);    // 18,432 ints
  u16*   qkvBT   = (u16*)(ws + 7695872);    // 98,304 fl
  u16*   B2combo = (u16*)(ws + 7794176);    // 65,536 fl : [256][512]
  u16*   ff1BT   = (u16*)(ws + 7859712);    // 131,072 fl
  u16*   ff2BT   = (u16*)(ws + 7990784);    // 131,072 fl
  u16*   sg1BT   = (u16*)(ws + 8121856);    // 8,192 fl -> end 8,130,048
  // aliases of qkv region (qkv fp32 dead after gather):
  u16*   h_bf     = (u16*)qkv;              // [0, 2,359,296) fl
  u16*   normed_bf= (u16*)(ws + 2359296);   // [2,359,296, 2,949,120) fl

  dim3 blk(256);

  // ---- ln1 + weight casts + scratch zeroing (fused) ----
  lncast_kernel<<<dim3(3537), blk, 0, stream>>>(x, xa_bf, xnhwc, ln1_g, ln1_b,
      qkv_w, out_w, pw_w, ff_w1, ff_w2, sg1_w,
      qkvBT, B2combo, ff1BT, ff2BT, sg1BT, csum);

  // ---- attention branch ----
  mgemm<2, 0, 1><<<dim3(12, 36), blk, 0, stream>>>(xa_bf, qkvBT, qkv, nullptr,
      256, 768, 768, nullptr, nullptr, nullptr, csum, 768, nullptr, nullptr, nullptr, nullptr);
  tkdw_kernel<<<dim3(4640), blk, 0, stream>>>(qkv, csum, idxb, xnhwc, dw_w, dw_b, A2);
  gather_kernel<<<dim3(72, BHN), blk, 0, stream>>>(qkv, idxb, Qg_bf, Kg_bf, VgT, vneg,
      csum, A2);
  attn_kernel<<<dim3(18, BHN), blk, 0, stream>>>(Qg_bf, Kg_bf, VgT, csum, vneg, idxb, A2);

  // ---- merged xs = [attn|dwc] @ B2 + pw_b  (K=512) ----
  mgemm<1, 7, 1><<<dim3(4, 72), blk, 0, stream>>>(A2, B2combo, nullptr, xs_bf,
      512, 256, 256, pw_b, nullptr, nullptr, cgm, 256, nullptr, nullptr, nullptr, nullptr);

  // ---- gates ----
  mgemm<1, 3, 0><<<dim3(1, 72), blk, 0, stream>>>(xs_bf, sg1BT, sga, nullptr,
      256, 32, 32, sg1_b, nullptr, nullptr, nullptr, 0, nullptr, nullptr, nullptr, nullptr);
  sgcg_kernel<<<dim3(98), blk, 0, stream>>>(sga, sg2_w, sg2_b, sgate,
      cgm, cg1_w, cg1_b, cg2_w, cg2_b, cgate);

  // ---- LN2 (x2 recomputed, not stored) ----
  gln_kernel<<<dim3(NROWS), blk, 0, stream>>>(xnhwc, xs_bf, sgate, cgate, gamma1,
      ln2_g, ln2_b, normed_bf);

  // ---- FFN ----
  mgemm<2, 4, 0><<<dim3(16, 36), blk, 0, stream>>>(normed_bf, ff1BT, nullptr, h_bf,
      256, 1024, 1024, ff_b1, nullptr, nullptr, nullptr, 0, nullptr, nullptr, nullptr, nullptr);
  mgemm<1, 5, 0><<<dim3(4, 72), blk, 0, stream>>>(h_bf, ff2BT, out, nullptr,
      1024, 256, 256, ff_b2, xnhwc, gamma2, nullptr, 0, xs_bf, sgate, cgate, gamma1);
}